// Round 6
// baseline (76.247 us; speedup 1.0000x reference)
//
#include <hip/hip_runtime.h>

// Ewald real-space sum, N=4096, aperiodic path.
// s_j  = sum_i q_i * erf(d_ij/sqrt(2)) / (d_ij + 1e-6)   (diagonal = 0)
// field_j = s_j/(2pi) + 2*SELF_C*q_j
// pot     = sum_j q_j*s_j/(4pi) + SELF_C*sum_j q_j^2
// out[0] = pot, out[1..N] = field
//
// R5: high-occupancy pairs (ICHUNK=32 -> 2048 blocks, 8 waves/SIMD target,
// __launch_bounds__(256,6)) + Newton-refined rsqrt (absmax back to ~1e-5).
// ws: float partial[128][4096] + float potblk[2048]. No memset needed —
// every ws slot we read is unconditionally written by ewald_pairs.

#define NPART 4096
#define JBLK 256
#define NJT (NPART / JBLK)          // 16
#define ICHUNK 32
#define NCHUNK (NPART / ICHUNK)     // 128

__global__ __launch_bounds__(JBLK, 6) void ewald_pairs(
        const float* __restrict__ pos,
        const float* __restrict__ q,
        float* __restrict__ partial,
        float* __restrict__ potblk) {
    __shared__ float4 sp[ICHUNK];   // x,y,z,q of the i-chunk
    __shared__ float red[4];

    const int tid = threadIdx.x;
    const int j = blockIdx.x * JBLK + tid;     // this thread's column
    const int i0 = blockIdx.y * ICHUNK;        // this block's i-chunk

    if (tid < ICHUNK) {
        const int i = i0 + tid;
        sp[tid] = make_float4(pos[3 * i], pos[3 * i + 1], pos[3 * i + 2], q[i]);
    }

    const float px = pos[3 * j];
    const float py = pos[3 * j + 1];
    const float pz = pos[3 * j + 2];
    const float qj = q[j];

    __syncthreads();

    float acc = 0.0f;
#pragma unroll 4
    for (int k = 0; k < ICHUNK; ++k) {
        float4 p = sp[k];  // broadcast read: all lanes same address, conflict-free
        float dx = p.x - px;
        float dy = p.y - py;
        float dz = p.z - pz;
        float d2 = fmaf(dx, dx, fmaf(dy, dy, dz * dz));
        float nh = -0.5f * d2;                      // reused by NR and exp
        float r0 = __builtin_amdgcn_rsqf(d2);
        float r  = r0 * fmaf(nh * r0, r0, 1.5f);    // one Newton step: ~exact 1/d
        float d  = d2 * r;
        float inv = r * fmaf(-1e-6f, r, 1.0f);      // 1/(d+1e-6), err O(eps^2/d^2)
        // A&S 7.1.26: t = 1/(1 + p*x), x = d/sqrt(2); p/sqrt(2) = 0.23165390651
        float t  = __builtin_amdgcn_rcpf(fmaf(0.23165390651f, d, 1.0f));
        float e  = __expf(nh);                      // exp(-x^2), x^2 = d2/2
        float poly = fmaf(fmaf(fmaf(fmaf(1.061405429f, t, -1.453152027f),
                                    t, 1.421413741f),
                               t, -0.284496736f),
                          t, 0.254829592f) * t;
        float w = fmaf(-poly, e, 1.0f) * inv;       // erf(x) * 1/(d+eps)
        w = ((i0 + k) == j) ? 0.0f : w;             // diagonal (NaN) -> exactly 0
        acc = fmaf(p.w, w, acc);                    // += q_i * w_ij
    }

    partial[blockIdx.y * NPART + j] = acc;          // coalesced, no atomics

    // block-reduce q_j * acc -> one value per block (for pot)
    float pj = qj * acc;
#pragma unroll
    for (int off = 32; off > 0; off >>= 1) pj += __shfl_down(pj, off);
    if ((tid & 63) == 0) red[tid >> 6] = pj;
    __syncthreads();
    if (tid == 0)
        potblk[blockIdx.y * NJT + blockIdx.x] = red[0] + red[1] + red[2] + red[3];
}

__global__ __launch_bounds__(256) void ewald_finalize(
        const float* __restrict__ q,
        const float* __restrict__ partial,   // [128][4096]
        const float* __restrict__ potblk,    // [2048]
        float* __restrict__ out) {
    const float INV2PI = 0.15915494309189535f;
    const float INV4PI = 0.07957747154594767f;
    const float SELFC  = 0.06349363593424097f;  // 1/(2pi)^1.5, sigma=1

    const int tid = threadIdx.x;

    if (blockIdx.x < NJT) {
        // field: sum the 128 chunk-partials for this j (coalesced per chunk)
        const int j = blockIdx.x * 256 + tid;
        float s = 0.0f;
#pragma unroll 8
        for (int c = 0; c < NCHUNK; ++c) s += partial[c * NPART + j];
        out[1 + j] = fmaf(s, INV2PI, q[j] * (2.0f * SELFC));
    } else {
        // pot: sum 2048 pre-reduced block values + self-interaction sum(q^2)
        float p = 0.0f;
#pragma unroll
        for (int c = 0; c < 8; ++c) p += potblk[c * 256 + tid];
        p *= INV4PI;
#pragma unroll
        for (int k = 0; k < 16; ++k) {
            float qq = q[tid * 16 + k];
            p = fmaf(qq * qq, SELFC, p);
        }
#pragma unroll
        for (int off = 32; off > 0; off >>= 1) p += __shfl_down(p, off);
        __shared__ float red[4];
        if ((tid & 63) == 0) red[tid >> 6] = p;
        __syncthreads();
        if (tid == 0) out[0] = red[0] + red[1] + red[2] + red[3];
    }
}

extern "C" void kernel_launch(void* const* d_in, const int* in_sizes, int n_in,
                              void* d_out, int out_size, void* d_ws, size_t ws_size,
                              hipStream_t stream) {
    const float* pos = (const float*)d_in[0];  // [N,3] f32
    const float* q   = (const float*)d_in[1];  // [N,1] f32
    float* out = (float*)d_out;                // [N+1] f32
    float* partial = (float*)d_ws;             // [128][4096]
    float* potblk  = partial + NCHUNK * NPART; // [2048]

    hipLaunchKernelGGL(ewald_pairs, dim3(NJT, NCHUNK), dim3(JBLK), 0, stream,
                       pos, q, partial, potblk);
    hipLaunchKernelGGL(ewald_finalize, dim3(NJT + 1), dim3(256), 0, stream,
                       q, partial, potblk, out);
}

// Round 8
// 73.894 us; speedup vs baseline: 1.0318x; 1.0318x over previous
//
#include <hip/hip_runtime.h>

// Ewald real-space sum, N=4096, aperiodic path.
// s_j  = sum_i q_i * erf(d_ij/sqrt(2)) / (d_ij + 1e-6)   (diagonal = 0)
// field_j = s_j/(2pi) + 2*SELF_C*q_j
// pot     = sum_j q_j*s_j/(4pi) + SELF_C*sum_j q_j^2
// out[0] = pot, out[1..N] = field
//
// R7 = R3 structure (ICHUNK=64, 1024 blocks — measured 72.03 vs 76.2 for the
// 2048-block variant) + inner-loop diet:
//   - no Newton step on rsq (absmax identical with/without: 3.9e-3 is
//     pot-summation-order noise, not rsqrt error)
//   - eps-correction dropped: w = erf(x) * r, since eps/d <= 2e-5 for the
//     minimum real pair distance (~0.05) — error far under existing noise.
// Diagonal handled by explicit cndmask (exact 0, NaN-free).
//
// ws: float partial[64][4096] (1 MB) + float potblk[1024]. No memset needed —
// every ws slot read by finalize is unconditionally written by ewald_pairs.

#define NPART 4096
#define JBLK 256
#define NJT (NPART / JBLK)          // 16
#define ICHUNK 64
#define NCHUNK (NPART / ICHUNK)     // 64

__global__ __launch_bounds__(JBLK) void ewald_pairs(
        const float* __restrict__ pos,
        const float* __restrict__ q,
        float* __restrict__ partial,
        float* __restrict__ potblk) {
    __shared__ float4 sp[ICHUNK];   // x,y,z,q of the i-chunk
    __shared__ float red[4];

    const int tid = threadIdx.x;
    const int j = blockIdx.x * JBLK + tid;     // this thread's column
    const int i0 = blockIdx.y * ICHUNK;        // this block's i-chunk

    if (tid < ICHUNK) {
        const int i = i0 + tid;
        sp[tid] = make_float4(pos[3 * i], pos[3 * i + 1], pos[3 * i + 2], q[i]);
    }

    const float px = pos[3 * j];
    const float py = pos[3 * j + 1];
    const float pz = pos[3 * j + 2];
    const float qj = q[j];

    __syncthreads();

    float acc = 0.0f;
#pragma unroll 8
    for (int k = 0; k < ICHUNK; ++k) {
        float4 p = sp[k];  // broadcast read: all lanes same address, conflict-free
        float dx = p.x - px;
        float dy = p.y - py;
        float dz = p.z - pz;
        float d2 = fmaf(dx, dx, fmaf(dy, dy, dz * dz));
        float r  = __builtin_amdgcn_rsqf(d2);       // 1/d (inf on diagonal, masked)
        float d  = d2 * r;                          // d
        // A&S 7.1.26: t = 1/(1 + p*x), x = d/sqrt(2); p/sqrt(2) = 0.23165390651
        float t  = __builtin_amdgcn_rcpf(fmaf(0.23165390651f, d, 1.0f));
        float e  = __expf(-0.5f * d2);              // exp(-x^2), x^2 = d2/2
        float poly = fmaf(fmaf(fmaf(fmaf(1.061405429f, t, -1.453152027f),
                                    t, 1.421413741f),
                               t, -0.284496736f),
                          t, 0.254829592f) * t;
        float w = fmaf(-poly, e, 1.0f) * r;         // erf(x)/d  (eps dropped)
        w = ((i0 + k) == j) ? 0.0f : w;             // diagonal -> exactly 0
        acc = fmaf(p.w, w, acc);                    // += q_i * w_ij
    }

    partial[blockIdx.y * NPART + j] = acc;          // coalesced, no atomics

    // block-reduce q_j * acc -> one value per block (for pot)
    float pj = qj * acc;
#pragma unroll
    for (int off = 32; off > 0; off >>= 1) pj += __shfl_down(pj, off);
    if ((tid & 63) == 0) red[tid >> 6] = pj;
    __syncthreads();
    if (tid == 0)
        potblk[blockIdx.y * NJT + blockIdx.x] = red[0] + red[1] + red[2] + red[3];
}

__global__ __launch_bounds__(256) void ewald_finalize(
        const float* __restrict__ q,
        const float* __restrict__ partial,   // [64][4096]
        const float* __restrict__ potblk,    // [1024]
        float* __restrict__ out) {
    const float INV2PI = 0.15915494309189535f;
    const float INV4PI = 0.07957747154594767f;
    const float SELFC  = 0.06349363593424097f;  // 1/(2pi)^1.5, sigma=1

    const int tid = threadIdx.x;

    if (blockIdx.x < NJT) {
        // field: sum the 64 chunk-partials for this j (coalesced per chunk)
        const int j = blockIdx.x * 256 + tid;
        float s = 0.0f;
#pragma unroll 8
        for (int c = 0; c < NCHUNK; ++c) s += partial[c * NPART + j];
        out[1 + j] = fmaf(s, INV2PI, q[j] * (2.0f * SELFC));
    } else {
        // pot: sum 1024 pre-reduced block values + self-interaction sum(q^2)
        float p = 0.0f;
#pragma unroll
        for (int c = 0; c < 4; ++c) p += potblk[c * 256 + tid];
        p *= INV4PI;
#pragma unroll
        for (int k = 0; k < 16; ++k) {
            float qq = q[tid * 16 + k];
            p = fmaf(qq * qq, SELFC, p);
        }
#pragma unroll
        for (int off = 32; off > 0; off >>= 1) p += __shfl_down(p, off);
        __shared__ float red[4];
        if ((tid & 63) == 0) red[tid >> 6] = p;
        __syncthreads();
        if (tid == 0) out[0] = red[0] + red[1] + red[2] + red[3];
    }
}

extern "C" void kernel_launch(void* const* d_in, const int* in_sizes, int n_in,
                              void* d_out, int out_size, void* d_ws, size_t ws_size,
                              hipStream_t stream) {
    const float* pos = (const float*)d_in[0];  // [N,3] f32
    const float* q   = (const float*)d_in[1];  // [N,1] f32
    float* out = (float*)d_out;                // [N+1] f32
    float* partial = (float*)d_ws;             // [64][4096]
    float* potblk  = partial + NCHUNK * NPART; // [1024]

    hipLaunchKernelGGL(ewald_pairs, dim3(NJT, NCHUNK), dim3(JBLK), 0, stream,
                       pos, q, partial, potblk);
    hipLaunchKernelGGL(ewald_finalize, dim3(NJT + 1), dim3(256), 0, stream,
                       q, partial, potblk, out);
}